// Round 5
// baseline (389.845 us; speedup 1.0000x reference)
//
#include <hip/hip_runtime.h>

// ---- problem constants ----
#define B_    2
#define N_    2049
#define NPAD  2112          // keys padded to multiple of 64
#define D_    1024
#define H_    16
#define DH    64
#define MROWS (B_ * N_)     // 4098
#define MPAD  4224          // MROWS padded to multiple of 128 (GEMM block tile)
#define QSCALE 0.18033688011117674f   // 0.125 * log2(e): softmax in exp2 domain

using bf16x8 = __attribute__((ext_vector_type(8))) short;
using f32x4  = __attribute__((ext_vector_type(4))) float;
using f32x16 = __attribute__((ext_vector_type(16))) float;

#define AS1 __attribute__((address_space(1)))
#define AS3 __attribute__((address_space(3)))

__device__ __forceinline__ float bf2f(short s) {
  union { unsigned u; float f; } a; a.u = ((unsigned)(unsigned short)s) << 16; return a.f;
}
__device__ __forceinline__ short f2bf(float f) {
  union { float f; unsigned u; } a; a.f = f;
  unsigned r = a.u + 0x7fffu + ((a.u >> 16) & 1u);   // round-to-nearest-even
  return (short)(r >> 16);
}
// truncation pack of two fp32 -> bf16x2
__device__ __forceinline__ unsigned pack_trunc(float lo, float hi) {
  union { float f; unsigned u; } a, b; a.f = lo; b.f = hi;
  return (b.u & 0xffff0000u) | (a.u >> 16);
}
// hardware 2^x (v_exp_f32)
__device__ __forceinline__ float hexp2(float x) { return __builtin_amdgcn_exp2f(x); }
// async global->LDS DMA, 16 B/lane; LDS dst is wave-uniform base (+lane*16 by HW)
__device__ __forceinline__ void dma16(const short* g, AS3 short* l) {
  __builtin_amdgcn_global_load_lds((const AS1 unsigned*)g, (AS3 unsigned*)l, 16, 0, 0);
}

// ---------------- LayerNorm: fp32 in -> bf16 out ----------------
__global__ __launch_bounds__(256) void ln_kernel(const float* __restrict__ x,
                                                 const float* __restrict__ gamma,
                                                 const float* __restrict__ beta,
                                                 short* __restrict__ xn) {
  int row = blockIdx.x;
  int tid = threadIdx.x;
  const float4 v = ((const float4*)(x + (size_t)row * D_))[tid];
  float s  = v.x + v.y + v.z + v.w;
  float ss = v.x * v.x + v.y * v.y + v.z * v.z + v.w * v.w;
  for (int o = 1; o < 64; o <<= 1) { s += __shfl_xor(s, o, 64); ss += __shfl_xor(ss, o, 64); }
  __shared__ float sb[4], s2b[4];
  int wid = tid >> 6;
  if ((tid & 63) == 0) { sb[wid] = s; s2b[wid] = ss; }
  __syncthreads();
  float st  = sb[0] + sb[1] + sb[2] + sb[3];
  float sst = s2b[0] + s2b[1] + s2b[2] + s2b[3];
  float mu  = st * (1.0f / D_);
  float var = sst * (1.0f / D_) - mu * mu;
  float rs  = rsqrtf(var + 1e-5f);
  const float4 g  = ((const float4*)gamma)[tid];
  const float4 be = ((const float4*)beta)[tid];
  short4 o4;
  o4.x = f2bf((v.x - mu) * rs * g.x + be.x);
  o4.y = f2bf((v.y - mu) * rs * g.y + be.y);
  o4.z = f2bf((v.z - mu) * rs * g.z + be.z);
  o4.w = f2bf((v.w - mu) * rs * g.w + be.w);
  ((short4*)(xn + (size_t)row * D_))[tid] = o4;
}

// ------------- LDS-tiled transpose+cast: fp32 [K][Nn] -> bf16 [Nn][K] -------------
__global__ __launch_bounds__(256) void transpose_tiled(const float* __restrict__ in,
                                                       short* __restrict__ out,
                                                       int K, int Nn) {
  __shared__ float T[64][65];       // +1 pad: column reads hit distinct banks
  int k0 = blockIdx.x * 64;         // K-tile base
  int n0 = blockIdx.y * 64;         // N-tile base
  int t = threadIdx.x;
  int r = t >> 2, c0 = (t & 3) * 16;
  const float* ip = in + (size_t)(k0 + r) * Nn + n0 + c0;
  #pragma unroll
  for (int j = 0; j < 4; ++j) {
    float4 v = *(const float4*)(ip + j * 4);
    T[r][c0 + j * 4 + 0] = v.x; T[r][c0 + j * 4 + 1] = v.y;
    T[r][c0 + j * 4 + 2] = v.z; T[r][c0 + j * 4 + 3] = v.w;
  }
  __syncthreads();
  // write: row n = n0 + (t>>2), orig-k cols c0..c0+15, bf16 coalesced
  bf16x8 w0, w1;
  #pragma unroll
  for (int j = 0; j < 8; ++j) {
    w0[j] = f2bf(T[c0 + j][r]);
    w1[j] = f2bf(T[c0 + 8 + j][r]);
  }
  short* op = out + (size_t)(n0 + r) * K + k0 + c0;
  *(bf16x8*)op = w0;
  *(bf16x8*)(op + 8) = w1;
}

// ------------- m97-style 128x128 GEMM: C[M][Ncols] = A[M][K] * BT[Ncols][K]^T -------------
#define BM 128
#define BK 32
template <typename OutT>
__global__ __launch_bounds__(256) void gemm128(const short* __restrict__ A,
                                               const short* __restrict__ BT,
                                               OutT* __restrict__ C,
                                               int Mstore, int Ncols, int K) {
  int lane = threadIdx.x & 63, wid = threadIdx.x >> 6;
  int quad = lane >> 4, l16 = lane & 15;
  int wr = wid >> 1, wc = wid & 1;
  int m0 = blockIdx.x * BM;
  int n0 = blockIdx.y * BM;

  __shared__ __align__(16) short Abuf[2][BM * BK];   // [row][k] row-major, 8 KB each
  __shared__ __align__(16) short Bbuf[2][BM * BK];
  AS3 short* AbufL = (AS3 short*)&Abuf[0][0];
  AS3 short* BbufL = (AS3 short*)&Bbuf[0][0];

  f32x4 acc[4][4] = {};

  int lrow = lane >> 2, lcol8 = (lane & 3) * 8;
  const short* Ag = A  + (size_t)(m0 + lrow) * K + lcol8;
  const short* Bg = BT + (size_t)(n0 + lrow) * K + lcol8;

  auto stage = [&](int kt, int bb) {
    int k0 = kt * BK;
    #pragma unroll
    for (int i = 0; i < 2; ++i) {
      int j = wid * 2 + i;                  // slab 0..7 (16 rows each)
      dma16(Ag + (size_t)j * 16 * K + k0, AbufL + bb * (BM * BK) + j * 512);
      dma16(Bg + (size_t)j * 16 * K + k0, BbufL + bb * (BM * BK) + j * 512);
    }
  };

  stage(0, 0);
  __syncthreads();

  int KT = K / BK;
  for (int kt = 0; kt < KT; ++kt) {
    int cur = kt & 1;
    if (kt + 1 < KT) stage(kt + 1, cur ^ 1);
    const short* Ab = &Abuf[cur][0];
    const short* Bb = &Bbuf[cur][0];
    bf16x8 af[4], bfr[4];
    #pragma unroll
    for (int s = 0; s < 4; ++s)
      af[s] = *(const bf16x8*)&Ab[(wr * 64 + s * 16 + l16) * BK + quad * 8];
    #pragma unroll
    for (int t = 0; t < 4; ++t)
      bfr[t] = *(const bf16x8*)&Bb[(wc * 64 + t * 16 + l16) * BK + quad * 8];
    #pragma unroll
    for (int s = 0; s < 4; ++s)
      #pragma unroll
      for (int t = 0; t < 4; ++t)
        acc[s][t] = __builtin_amdgcn_mfma_f32_16x16x32_bf16(af[s], bfr[t], acc[s][t], 0, 0, 0);
    __syncthreads();
  }

  #pragma unroll
  for (int s = 0; s < 4; ++s)
    #pragma unroll
    for (int r = 0; r < 4; ++r) {
      int row = m0 + wr * 64 + s * 16 + quad * 4 + r;
      if (row < Mstore) {
        size_t rb = (size_t)row * Ncols + n0 + wc * 64;
        #pragma unroll
        for (int t = 0; t < 4; ++t) {
          float val = acc[s][t][r];
          if constexpr (sizeof(OutT) == 2)
            C[rb + t * 16 + l16] = (OutT)(unsigned short)f2bf(val);
          else
            C[rb + t * 16 + l16] = (OutT)val;
        }
      }
    }
}

// ------------- RoPE v2 (tiled, coalesced): block = (64 tokens) x (one bh) -------------
__global__ __launch_bounds__(256) void rope_kernel(const short* __restrict__ qkv,
                                                   short* __restrict__ qg,
                                                   short* __restrict__ kg,
                                                   short* __restrict__ vT) {
  int bh = blockIdx.y;              // 0..31
  int n0 = blockIdx.x * 64;         // 33 tiles cover NPAD
  int b = bh >> 4, h = bh & 15;
  int t = threadIdx.x;
  int nl = t >> 2;                  // token within tile
  int p  = t & 3;                   // dh part: pairs (p*8+j, p*8+j+32)
  int n  = n0 + nl;
  size_t hb = (size_t)bh * NPAD * DH;
  size_t ob = hb + (size_t)n * DH;

  __shared__ short Vt[64][66];      // [n-local][dh], pad 2 to de-stride column reads

  bf16x8 oq1 = {}, oq2 = {}, ok1 = {}, ok2 = {};
  short v1s[8] = {}, v2s[8] = {};
  if (n < N_) {
    size_t ib = ((size_t)(b * N_ + n)) * 3072 + h * DH;
    bf16x8 q1v = *(const bf16x8*)(qkv + ib + p * 8);
    bf16x8 q2v = *(const bf16x8*)(qkv + ib + 32 + p * 8);
    bf16x8 k1v = *(const bf16x8*)(qkv + ib + 1024 + p * 8);
    bf16x8 k2v = *(const bf16x8*)(qkv + ib + 1024 + 32 + p * 8);
    bf16x8 v1v = *(const bf16x8*)(qkv + ib + 2048 + p * 8);
    bf16x8 v2v = *(const bf16x8*)(qkv + ib + 2048 + 32 + p * 8);
    #pragma unroll
    for (int j = 0; j < 8; ++j) {
      int i = p * 8 + j;
      float q1 = bf2f(q1v[j]), q2 = bf2f(q2v[j]);
      float k1 = bf2f(k1v[j]), k2 = bf2f(k2v[j]);
      if (n > 0) {              // cls token excluded from RoPE
        float ang = (float)(n - 1) * powf(10000.0f, -(float)i * (1.0f / 32.0f));
        float sn, cs; sincosf(ang, &sn, &cs);
        float nq1 = q1 * cs - q2 * sn, nq2 = q2 * cs + q1 * sn;
        float nk1 = k1 * cs - k2 * sn, nk2 = k2 * cs + k1 * sn;
        q1 = nq1; q2 = nq2; k1 = nk1; k2 = nk2;
      }
      oq1[j] = f2bf(q1 * QSCALE); oq2[j] = f2bf(q2 * QSCALE);  // scale*log2e folded into q
      ok1[j] = f2bf(k1); ok2[j] = f2bf(k2);
      v1s[j] = v1v[j]; v2s[j] = v2v[j];
    }
  }
  // q/k row-major stores (zero rows for padding)
  *(bf16x8*)(qg + ob + p * 8)      = oq1;
  *(bf16x8*)(qg + ob + 32 + p * 8) = oq2;
  *(bf16x8*)(kg + ob + p * 8)      = ok1;
  *(bf16x8*)(kg + ob + 32 + p * 8) = ok2;
  // stage V to LDS
  #pragma unroll
  for (int j = 0; j < 8; ++j) {
    Vt[nl][p * 8 + j]      = v1s[j];
    Vt[nl][32 + p * 8 + j] = v2s[j];
  }
  __syncthreads();
  // vT write: thread covers dh=t>>2, 16 consecutive tokens
  int d = t >> 2, c0 = (t & 3) * 16;
  bf16x8 w0, w1;
  #pragma unroll
  for (int m = 0; m < 8; ++m) { w0[m] = Vt[c0 + m][d]; w1[m] = Vt[c0 + 8 + m][d]; }
  *(bf16x8*)(vT + hb + (size_t)d * NPAD + n0 + c0)     = w0;
  *(bf16x8*)(vT + hb + (size_t)d * NPAD + n0 + c0 + 8) = w1;
}

// ------------- flash attention v6: barrier-free, register-prefetched K, no LDS ----------
// Round-3 evidence: in-reg softmax removed all LDS conflicts yet time was IDENTICAL to
// round 0 (110.2 vs 110.4 us) -> inner compute is not the critical path. Per-wave-iteration
// wall latency ~7000 cy vs ~1000 cy compute: the vmcnt(0)+s_barrier lockstep per tile is
// the stall (m233: 2-phase = ~72% overhead). This version removes ALL inter-wave coupling:
// 32-key tiles, K-fragments prefetched one tile ahead into REGISTERS (plain loads; the
// compiler tracks reg deps and emits counted vmcnt itself), V loaded at iteration top and
// consumed after softmax. No LDS, no barriers, no DMA. 2-wave blocks (waves independent),
// __launch_bounds__(128,4) -> <=128 VGPR -> 16 waves/CU. L2 traffic ~1.2 GB (<34.5 TB/s
// ceiling at target time); per-XCD K/V/Q working set ~3.2 MB stays L2-resident via swizzle.
// Layouts (mfma_f32_32x32x16_bf16): A: lane l holds A[m=l&31][k=(l>>5)*8+j];
// B: B[k=(l>>5)*8+j][n=l&31]; C/D: col=l&31, row=(reg&3)+8*(reg>>2)+4*(l>>5).
__global__ __launch_bounds__(128, 4) void attn_kernel(const short* __restrict__ qg,
                                                      const short* __restrict__ kg,
                                                      const short* __restrict__ vT,
                                                      short* __restrict__ Opart,
                                                      float* __restrict__ lpart) {
  // XCD-clustered decode: blk&7 -> XCD; 4 heads per XCD
  int blk = blockIdx.x;             // 0..2111
  int xcd = blk & 7;
  int t_  = blk >> 3;               // 0..263
  int bh  = xcd * 4 + (t_ & 3);
  int u   = t_ >> 2;                // 0..65
  int ks  = (u >= 33) ? 1 : 0;
  int qblk = u - ks * 33;           // 0..32
  int kt0 = ks * 33;                // 33 tiles of 32 keys per split half

  int lane = threadIdx.x & 63, wid = threadIdx.x >> 6;   // wid 0..1, waves independent
  int q    = lane & 31;             // q-column within wave's 32-row tile
  int half = lane >> 5;             // 0/1: lane half
  int q0   = qblk * 64 + wid * 32;
  if (q0 >= N_) return;             // fully-dead q-tile (no barriers -> safe)

  size_t hb = (size_t)bh * NPAD * DH;
  const short* kg_hb = kg + hb;
  const short* vT_hb = vT + hb;

  // Q B-frags (persistent): lane reads its q-row; k = kstep*16 + half*8 + j
  int qr = q0 + q;                  // < NPAD; rows >= N_ produce columns never stored
  const short* qp = qg + hb + (size_t)qr * DH + half * 8;
  bf16x8 qf[4];
  #pragma unroll
  for (int s = 0; s < 4; ++s) qf[s] = *(const bf16x8*)(qp + s * 16);

  f32x16 o0 = {}, o1 = {};          // O^T[dh = m*32 + (reg&3)+8*(reg>>2)+4*half][q]
  float lrun = 0.0f;

  // K A-frag loader for one 32-key tile (4 x global_load_dwordx4, rows k0+q)
  const short* kQrow = kg_hb + (size_t)q * DH + half * 8;
  auto loadK = [&](int t, bf16x8 (&kf)[4]) {
    const short* p = kQrow + (size_t)(kt0 + t) * 32 * DH;
    #pragma unroll
    for (int s = 0; s < 4; ++s) kf[s] = *(const bf16x8*)(p + s * 16);
  };

  bf16x8 kA[4], kB[4];
  loadK(0, kA);                     // prologue: first tile in flight

  auto body = [&](int t, bf16x8 (&kc)[4], bf16x8 (&kn)[4], bool pf) {
    int k0 = (kt0 + t) * 32;
    // V A-frags for this tile (issued early; consumed after softmax)
    bf16x8 vf0[2], vf1[2];
    #pragma unroll
    for (int s = 0; s < 2; ++s) {
      vf0[s] = *(const bf16x8*)(vT_hb + (size_t)q * NPAD + k0 + s * 16 + half * 8);
      vf1[s] = *(const bf16x8*)(vT_hb + (size_t)(32 + q) * NPAD + k0 + s * 16 + half * 8);
    }
    if (pf) loadK(t + 1, kn);       // register prefetch: next K tile

    // ---- S^T = K * Q^T over dh (4 k-steps of 16) ----
    f32x16 sA = {};
    __builtin_amdgcn_s_setprio(1);
    #pragma unroll
    for (int s = 0; s < 4; ++s)
      sA = __builtin_amdgcn_mfma_f32_32x32x16_bf16(kc[s], qf[s], sA, 0, 0, 0);
    __builtin_amdgcn_s_setprio(0);

    // mask invalid keys (only the 2 tiles straddling/above N_; wave-uniform branch)
    if (k0 + 32 > N_) {
      #pragma unroll
      for (int rr = 0; rr < 16; ++rr) {
        int key = (rr & 3) + 8 * (rr >> 2) + 4 * half;
        if (k0 + key >= N_) sA[rr] = -1e30f;
      }
    }

    // ---- p = 2^s in place + per-lane row-sum ----
    float vsum = 0.0f;
    #pragma unroll
    for (int rr = 0; rr < 16; ++rr) { sA[rr] = hexp2(sA[rr]); vsum += sA[rr]; }
    lrun += vsum;

    // ---- pack pairs + permlane32_swap -> P^T B-frags, in registers (round-3-verified) ----
    unsigned w[2][4];
    #pragma unroll
    for (int fs = 0; fs < 2; ++fs) {
      int b0 = fs * 8;
      unsigned X1 = pack_trunc(sA[b0 + 0], sA[b0 + 1]);
      unsigned X2 = pack_trunc(sA[b0 + 2], sA[b0 + 3]);
      unsigned Y1 = pack_trunc(sA[b0 + 4], sA[b0 + 5]);
      unsigned Y2 = pack_trunc(sA[b0 + 6], sA[b0 + 7]);
      asm("v_permlane32_swap_b32 %0, %1" : "+v"(X1), "+v"(Y1));
      asm("v_permlane32_swap_b32 %0, %1" : "+v"(X2), "+v"(Y2));
      w[fs][0] = X1; w[fs][1] = X2; w[fs][2] = Y1; w[fs][3] = Y2;
    }

    // ---- O^T += V^T * P^T (2 k-steps of 16 keys) ----
    __builtin_amdgcn_s_setprio(1);
    #pragma unroll
    for (int kst = 0; kst < 2; ++kst) {
      union { unsigned u[4]; bf16x8 v; } bw;
      bw.u[0] = w[kst][0]; bw.u[1] = w[kst][1]; bw.u[2] = w[kst][2]; bw.u[3] = w[kst][3];
      o0 = __builtin_amdgcn_mfma_f32_32x32x16_bf16(vf0[kst], bw.v, o0, 0, 0, 0);
      o1 = __builtin_amdgcn_mfma_f32_32x32x16_bf16(vf1[kst], bw.v, o1, 0, 0, 0);
    }
    __builtin_amdgcn_s_setprio(0);
  };

  // 33 tiles: 16 double-bodies + tail (static A/B roles -> no runtime-indexed frags)
  #pragma unroll 1
  for (int i = 0; i < 16; ++i) {
    body(2 * i,     kA, kB, true);
    body(2 * i + 1, kB, kA, true);
  }
  body(32, kA, kB, false);

  lrun += __shfl_xor(lrun, 32, 64);   // fold the two lane-halves of each q-column

  // epilogue: unnormalized partial write. Opart[ks][bh][NPAD][64] bf16, lpart[ks][bh][NPAD]
  int qrow = q0 + q;
  if (qrow < N_) {
    size_t ob = (((size_t)ks * 32 + bh) * NPAD + qrow) * 64;
    #pragma unroll
    for (int m = 0; m < 2; ++m) {
      #pragma unroll
      for (int gq = 0; gq < 4; ++gq) {
        float a0 = m ? o1[gq * 4 + 0] : o0[gq * 4 + 0];
        float a1 = m ? o1[gq * 4 + 1] : o0[gq * 4 + 1];
        float a2 = m ? o1[gq * 4 + 2] : o0[gq * 4 + 2];
        float a3 = m ? o1[gq * 4 + 3] : o0[gq * 4 + 3];
        short4 st;
        st.x = f2bf(a0); st.y = f2bf(a1); st.z = f2bf(a2); st.w = f2bf(a3);
        int dh = m * 32 + gq * 8 + half * 4;
        *(short4*)(Opart + ob + dh) = st;
      }
    }
    if (half == 0) lpart[((size_t)ks * 32 + bh) * NPAD + qrow] = lrun;
  }
}

// ------------- combine: attn_out = (O0+O1)/(l0+l1), bf16 -------------
__global__ __launch_bounds__(256) void combine_kernel(const short* __restrict__ Opart,
                                                      const float* __restrict__ lpart,
                                                      short* __restrict__ attn_out) {
  int idx = blockIdx.x * 256 + threadIdx.x;
  const int total = 32 * N_ * 16;          // 4 dh elems per thread
  if (idx >= total) return;
  int c4 = idx & 15;
  int t = idx >> 4;
  int n = t % N_;
  int bh = t / N_;
  int b = bh >> 4, h = bh & 15;
  const size_t halfO = (size_t)32 * NPAD * 64;
  size_t off = ((size_t)bh * NPAD + n) * 64 + c4 * 4;
  short4 a  = *(const short4*)(Opart + off);
  short4 bb = *(const short4*)(Opart + halfO + off);
  float la = lpart[(size_t)bh * NPAD + n];
  float lb = lpart[(size_t)32 * NPAD + (size_t)bh * NPAD + n];
  float inv = 1.0f / (la + lb);
  short4 st;
  st.x = f2bf((bf2f(a.x) + bf2f(bb.x)) * inv);
  st.y = f2bf((bf2f(a.y) + bf2f(bb.y)) * inv);
  st.z = f2bf((bf2f(a.z) + bf2f(bb.z)) * inv);
  st.w = f2bf((bf2f(a.w) + bf2f(bb.w)) * inv);
  size_t rowb = ((size_t)(b * N_ + n)) * (H_ * DH) + h * DH + c4 * 4;
  *(short4*)(attn_out + rowb) = st;
}

// ---------------- launcher ----------------
extern "C" void kernel_launch(void* const* d_in, const int* in_sizes, int n_in,
                              void* d_out, int out_size, void* d_ws, size_t ws_size,
                              hipStream_t stream) {
  const float* x     = (const float*)d_in[0];
  const float* gamma = (const float*)d_in[1];
  const float* beta  = (const float*)d_in[2];
  const float* w_qkv = (const float*)d_in[3];
  const float* w_out = (const float*)d_in[4];

  short* wqkvT = (short*)d_ws;                         // [3072][1024]
  short* woutT = wqkvT + (size_t)3072 * 1024;          // [1024][1024]
  short* xn    = woutT + (size_t)1024 * 1024;          // [4224][1024] (aliased as attn_out later)
  short* qkv   = xn    + (size_t)MPAD * 1024;          // [4224][3072] (aliased as Opart/lpart later)
  short* qg    = qkv   + (size_t)MPAD * 3072;          // [2][16][2112][64]
  short* kg    = qg    + (size_t)B_ * H_ * NPAD * DH;
  short* vTg   = kg    + (size_t)B_ * H_ * NPAD * DH;  // [2][16][64][2112]
  short* attn_out = xn;                                // xn dead after QKV GEMM
  short* Opart = qkv;                                  // [2][32][2112][64] bf16 (qkv dead after rope)
  float* lpart = (float*)(qkv + (size_t)2 * 32 * NPAD * 64);  // [2][32][2112] fp32

  ln_kernel<<<MROWS, 256, 0, stream>>>(x, gamma, beta, xn);
  {
    dim3 g(1024 / 64, 3072 / 64);          // LDS-tiled coalesced transpose
    transpose_tiled<<<g, 256, 0, stream>>>(w_qkv, wqkvT, 1024, 3072);
  }
  {
    dim3 g(1024 / 64, 1024 / 64);
    transpose_tiled<<<g, 256, 0, stream>>>(w_out, woutT, 1024, 1024);
  }
  {
    dim3 g(MPAD / 128, 3072 / 128);        // 33 x 24
    gemm128<unsigned short><<<g, 256, 0, stream>>>(xn, wqkvT, (unsigned short*)qkv, MROWS, 3072, 1024);
  }
  {
    dim3 g(33, 32);                        // 64-token tiles x (b,h)
    rope_kernel<<<g, 256, 0, stream>>>(qkv, qg, kg, vTg);
  }
  // 2112 blocks x 2 independent waves: 8 XCD x (4 bh x (2 ks x 33 qblk))
  attn_kernel<<<2112, 128, 0, stream>>>(qg, kg, vTg, Opart, lpart);
  combine_kernel<<<(32 * N_ * 16 + 255) / 256, 256, 0, stream>>>(Opart, lpart, attn_out);
  {
    dim3 g(MPAD / 128, 1024 / 128);        // 33 x 8
    gemm128<float><<<g, 256, 0, stream>>>(attn_out, woutT, (float*)d_out, MROWS, 1024, 1024);
  }
}

// Round 6
// 292.860 us; speedup vs baseline: 1.3312x; 1.3312x over previous
//
#include <hip/hip_runtime.h>

// ---- problem constants ----
#define B_    2
#define N_    2049
#define NPAD  2112          // keys padded to multiple of 64
#define D_    1024
#define H_    16
#define DH    64
#define MROWS (B_ * N_)     // 4098
#define MPAD  4224          // MROWS padded to multiple of 128 (GEMM block tile)
#define QSCALE 0.18033688011117674f   // 0.125 * log2(e): softmax in exp2 domain

using bf16x8 = __attribute__((ext_vector_type(8))) short;
using f32x4  = __attribute__((ext_vector_type(4))) float;
using f32x16 = __attribute__((ext_vector_type(16))) float;

#define AS1 __attribute__((address_space(1)))
#define AS3 __attribute__((address_space(3)))

__device__ __forceinline__ float bf2f(short s) {
  union { unsigned u; float f; } a; a.u = ((unsigned)(unsigned short)s) << 16; return a.f;
}
__device__ __forceinline__ short f2bf(float f) {
  union { float f; unsigned u; } a; a.f = f;
  unsigned r = a.u + 0x7fffu + ((a.u >> 16) & 1u);   // round-to-nearest-even
  return (short)(r >> 16);
}
// truncation pack of two fp32 -> bf16x2
__device__ __forceinline__ unsigned pack_trunc(float lo, float hi) {
  union { float f; unsigned u; } a, b; a.f = lo; b.f = hi;
  return (b.u & 0xffff0000u) | (a.u >> 16);
}
// hardware 2^x (v_exp_f32)
__device__ __forceinline__ float hexp2(float x) { return __builtin_amdgcn_exp2f(x); }
// async global->LDS DMA, 16 B/lane; LDS dst is wave-uniform base (+lane*16 by HW)
__device__ __forceinline__ void dma16(const short* g, AS3 short* l) {
  __builtin_amdgcn_global_load_lds((const AS1 unsigned*)g, (AS3 unsigned*)l, 16, 0, 0);
}

// ---------------- LayerNorm: fp32 in -> bf16 out ----------------
__global__ __launch_bounds__(256) void ln_kernel(const float* __restrict__ x,
                                                 const float* __restrict__ gamma,
                                                 const float* __restrict__ beta,
                                                 short* __restrict__ xn) {
  int row = blockIdx.x;
  int tid = threadIdx.x;
  const float4 v = ((const float4*)(x + (size_t)row * D_))[tid];
  float s  = v.x + v.y + v.z + v.w;
  float ss = v.x * v.x + v.y * v.y + v.z * v.z + v.w * v.w;
  for (int o = 1; o < 64; o <<= 1) { s += __shfl_xor(s, o, 64); ss += __shfl_xor(ss, o, 64); }
  __shared__ float sb[4], s2b[4];
  int wid = tid >> 6;
  if ((tid & 63) == 0) { sb[wid] = s; s2b[wid] = ss; }
  __syncthreads();
  float st  = sb[0] + sb[1] + sb[2] + sb[3];
  float sst = s2b[0] + s2b[1] + s2b[2] + s2b[3];
  float mu  = st * (1.0f / D_);
  float var = sst * (1.0f / D_) - mu * mu;
  float rs  = rsqrtf(var + 1e-5f);
  const float4 g  = ((const float4*)gamma)[tid];
  const float4 be = ((const float4*)beta)[tid];
  short4 o4;
  o4.x = f2bf((v.x - mu) * rs * g.x + be.x);
  o4.y = f2bf((v.y - mu) * rs * g.y + be.y);
  o4.z = f2bf((v.z - mu) * rs * g.z + be.z);
  o4.w = f2bf((v.w - mu) * rs * g.w + be.w);
  ((short4*)(xn + (size_t)row * D_))[tid] = o4;
}

// ------------- LDS-tiled transpose+cast: fp32 [K][Nn] -> bf16 [Nn][K] -------------
__global__ __launch_bounds__(256) void transpose_tiled(const float* __restrict__ in,
                                                       short* __restrict__ out,
                                                       int K, int Nn) {
  __shared__ float T[64][65];       // +1 pad: column reads hit distinct banks
  int k0 = blockIdx.x * 64;         // K-tile base
  int n0 = blockIdx.y * 64;         // N-tile base
  int t = threadIdx.x;
  int r = t >> 2, c0 = (t & 3) * 16;
  const float* ip = in + (size_t)(k0 + r) * Nn + n0 + c0;
  #pragma unroll
  for (int j = 0; j < 4; ++j) {
    float4 v = *(const float4*)(ip + j * 4);
    T[r][c0 + j * 4 + 0] = v.x; T[r][c0 + j * 4 + 1] = v.y;
    T[r][c0 + j * 4 + 2] = v.z; T[r][c0 + j * 4 + 3] = v.w;
  }
  __syncthreads();
  // write: row n = n0 + (t>>2), orig-k cols c0..c0+15, bf16 coalesced
  bf16x8 w0, w1;
  #pragma unroll
  for (int j = 0; j < 8; ++j) {
    w0[j] = f2bf(T[c0 + j][r]);
    w1[j] = f2bf(T[c0 + 8 + j][r]);
  }
  short* op = out + (size_t)(n0 + r) * K + k0 + c0;
  *(bf16x8*)op = w0;
  *(bf16x8*)(op + 8) = w1;
}

// ------------- m97-style 128x128 GEMM: C[M][Ncols] = A[M][K] * BT[Ncols][K]^T -------------
#define BM 128
#define BK 32
template <typename OutT>
__global__ __launch_bounds__(256) void gemm128(const short* __restrict__ A,
                                               const short* __restrict__ BT,
                                               OutT* __restrict__ C,
                                               int Mstore, int Ncols, int K) {
  int lane = threadIdx.x & 63, wid = threadIdx.x >> 6;
  int quad = lane >> 4, l16 = lane & 15;
  int wr = wid >> 1, wc = wid & 1;
  int m0 = blockIdx.x * BM;
  int n0 = blockIdx.y * BM;

  __shared__ __align__(16) short Abuf[2][BM * BK];   // [row][k] row-major, 8 KB each
  __shared__ __align__(16) short Bbuf[2][BM * BK];
  AS3 short* AbufL = (AS3 short*)&Abuf[0][0];
  AS3 short* BbufL = (AS3 short*)&Bbuf[0][0];

  f32x4 acc[4][4] = {};

  int lrow = lane >> 2, lcol8 = (lane & 3) * 8;
  const short* Ag = A  + (size_t)(m0 + lrow) * K + lcol8;
  const short* Bg = BT + (size_t)(n0 + lrow) * K + lcol8;

  auto stage = [&](int kt, int bb) {
    int k0 = kt * BK;
    #pragma unroll
    for (int i = 0; i < 2; ++i) {
      int j = wid * 2 + i;                  // slab 0..7 (16 rows each)
      dma16(Ag + (size_t)j * 16 * K + k0, AbufL + bb * (BM * BK) + j * 512);
      dma16(Bg + (size_t)j * 16 * K + k0, BbufL + bb * (BM * BK) + j * 512);
    }
  };

  stage(0, 0);
  __syncthreads();

  int KT = K / BK;
  for (int kt = 0; kt < KT; ++kt) {
    int cur = kt & 1;
    if (kt + 1 < KT) stage(kt + 1, cur ^ 1);
    const short* Ab = &Abuf[cur][0];
    const short* Bb = &Bbuf[cur][0];
    bf16x8 af[4], bfr[4];
    #pragma unroll
    for (int s = 0; s < 4; ++s)
      af[s] = *(const bf16x8*)&Ab[(wr * 64 + s * 16 + l16) * BK + quad * 8];
    #pragma unroll
    for (int t = 0; t < 4; ++t)
      bfr[t] = *(const bf16x8*)&Bb[(wc * 64 + t * 16 + l16) * BK + quad * 8];
    #pragma unroll
    for (int s = 0; s < 4; ++s)
      #pragma unroll
      for (int t = 0; t < 4; ++t)
        acc[s][t] = __builtin_amdgcn_mfma_f32_16x16x32_bf16(af[s], bfr[t], acc[s][t], 0, 0, 0);
    __syncthreads();
  }

  #pragma unroll
  for (int s = 0; s < 4; ++s)
    #pragma unroll
    for (int r = 0; r < 4; ++r) {
      int row = m0 + wr * 64 + s * 16 + quad * 4 + r;
      if (row < Mstore) {
        size_t rb = (size_t)row * Ncols + n0 + wc * 64;
        #pragma unroll
        for (int t = 0; t < 4; ++t) {
          float val = acc[s][t][r];
          if constexpr (sizeof(OutT) == 2)
            C[rb + t * 16 + l16] = (OutT)(unsigned short)f2bf(val);
          else
            C[rb + t * 16 + l16] = (OutT)val;
        }
      }
    }
}

// ------------- RoPE v2 (tiled, coalesced): block = (64 tokens) x (one bh) -------------
__global__ __launch_bounds__(256) void rope_kernel(const short* __restrict__ qkv,
                                                   short* __restrict__ qg,
                                                   short* __restrict__ kg,
                                                   short* __restrict__ vT) {
  int bh = blockIdx.y;              // 0..31
  int n0 = blockIdx.x * 64;         // 33 tiles cover NPAD
  int b = bh >> 4, h = bh & 15;
  int t = threadIdx.x;
  int nl = t >> 2;                  // token within tile
  int p  = t & 3;                   // dh part: pairs (p*8+j, p*8+j+32)
  int n  = n0 + nl;
  size_t hb = (size_t)bh * NPAD * DH;
  size_t ob = hb + (size_t)n * DH;

  __shared__ short Vt[64][66];      // [n-local][dh], pad 2 to de-stride column reads

  bf16x8 oq1 = {}, oq2 = {}, ok1 = {}, ok2 = {};
  short v1s[8] = {}, v2s[8] = {};
  if (n < N_) {
    size_t ib = ((size_t)(b * N_ + n)) * 3072 + h * DH;
    bf16x8 q1v = *(const bf16x8*)(qkv + ib + p * 8);
    bf16x8 q2v = *(const bf16x8*)(qkv + ib + 32 + p * 8);
    bf16x8 k1v = *(const bf16x8*)(qkv + ib + 1024 + p * 8);
    bf16x8 k2v = *(const bf16x8*)(qkv + ib + 1024 + 32 + p * 8);
    bf16x8 v1v = *(const bf16x8*)(qkv + ib + 2048 + p * 8);
    bf16x8 v2v = *(const bf16x8*)(qkv + ib + 2048 + 32 + p * 8);
    #pragma unroll
    for (int j = 0; j < 8; ++j) {
      int i = p * 8 + j;
      float q1 = bf2f(q1v[j]), q2 = bf2f(q2v[j]);
      float k1 = bf2f(k1v[j]), k2 = bf2f(k2v[j]);
      if (n > 0) {              // cls token excluded from RoPE
        float ang = (float)(n - 1) * powf(10000.0f, -(float)i * (1.0f / 32.0f));
        float sn, cs; sincosf(ang, &sn, &cs);
        float nq1 = q1 * cs - q2 * sn, nq2 = q2 * cs + q1 * sn;
        float nk1 = k1 * cs - k2 * sn, nk2 = k2 * cs + k1 * sn;
        q1 = nq1; q2 = nq2; k1 = nk1; k2 = nk2;
      }
      oq1[j] = f2bf(q1 * QSCALE); oq2[j] = f2bf(q2 * QSCALE);  // scale*log2e folded into q
      ok1[j] = f2bf(k1); ok2[j] = f2bf(k2);
      v1s[j] = v1v[j]; v2s[j] = v2v[j];
    }
  }
  // q/k row-major stores (zero rows for padding)
  *(bf16x8*)(qg + ob + p * 8)      = oq1;
  *(bf16x8*)(qg + ob + 32 + p * 8) = oq2;
  *(bf16x8*)(kg + ob + p * 8)      = ok1;
  *(bf16x8*)(kg + ob + 32 + p * 8) = ok2;
  // stage V to LDS
  #pragma unroll
  for (int j = 0; j < 8; ++j) {
    Vt[nl][p * 8 + j]      = v1s[j];
    Vt[nl][32 + p * 8 + j] = v2s[j];
  }
  __syncthreads();
  // vT write: thread covers dh=t>>2, 16 consecutive tokens
  int d = t >> 2, c0 = (t & 3) * 16;
  bf16x8 w0, w1;
  #pragma unroll
  for (int m = 0; m < 8; ++m) { w0[m] = Vt[c0 + m][d]; w1[m] = Vt[c0 + 8 + m][d]; }
  *(bf16x8*)(vT + hb + (size_t)d * NPAD + n0 + c0)     = w0;
  *(bf16x8*)(vT + hb + (size_t)d * NPAD + n0 + c0 + 8) = w1;
}

// ------------- flash attention v7: r3 base + triple-buffer K + counted vmcnt ------------
// Evidence ledger: r1/r5 (no DMA dedup) -> L2 thrash, WRITE 100-165MB, 215us. r0/r3
// (lockstep DMA) -> clean L2 (FETCH 13/WRITE 17MB) but 110us with MfmaUtil 13%: the
// __syncthreads() vmcnt(0) drains the SAME-iteration stage -> prefetch distance 0, every
// iteration eats full DMA latency (T4/m218: counted-vs-drain = +38-73%).
// v7: stage 2 tiles ahead into Kbuf[3]; raw s_barrier with vmcnt(2) guard. In-order vmcnt
// retirement means the compiler's own V-register waits (V issued after DMA(kt), before
// DMA(kt+1)) transitively retire DMA(kt) -> guard is ~free, prefetch never drained.
// sched_barrier(0) pins V-issue-before-DMA-issue so compiler reordering can't silently
// recreate the drain. Buffer safety: wave overwrites buf[(kt+2)%3] only after barrier(kt),
// by which point all waves' reads of that buffer (iter kt-1) are complete.
// Layouts (mfma_f32_32x32x16_bf16): A: lane l holds A[m=l&31][k=(l>>5)*8+j];
// B: B[k=(l>>5)*8+j][n=l&31]; C/D: col=l&31, row=(reg&3)+8*(reg>>2)+4*(l>>5).
__global__ __launch_bounds__(256, 3) void attn_kernel(const short* __restrict__ qg,
                                                      const short* __restrict__ kg,
                                                      const short* __restrict__ vT,
                                                      short* __restrict__ Opart,
                                                      float* __restrict__ lpart) {
  // XCD-clustered decode: blk&7 -> XCD; 4 heads per XCD
  int blk = blockIdx.x;             // 0..1087
  int xcd = blk & 7;
  int t_  = blk >> 3;               // 0..135
  int bh  = xcd * 4 + (t_ & 3);
  int u   = t_ >> 2;                // 0..33
  int ks  = (u >= 17) ? 1 : 0;
  int qblk = u - ks * 17;           // 0..16
  int kt0 = ks * 17, kt1 = ks ? 32 : 16;   // inclusive key-tile range

  int lane = threadIdx.x & 63, wid = threadIdx.x >> 6;
  int q    = lane & 31;             // q-column within wave's 32-row tile
  int half = lane >> 5;             // 0/1: lane half
  int q0   = qblk * 128 + wid * 32;
  size_t hb = (size_t)bh * NPAD * DH;
  const short* kg_hb = kg + hb;
  const short* vT_hb = vT + hb;

  __shared__ __align__(16) short Kbuf[3][8 * 512];   // 24 KB, triple-buffered
  AS3 short* KbufL = (AS3 short*)&Kbuf[0][0];
  const short* KbufR = &Kbuf[0][0];

  // Q B-frags (persistent): lane reads its q-row; k = kstep*16 + half*8 + j
  int qr = q0 + q; if (qr >= NPAD) qr = 0;   // clamp; garbage column never stored
  const short* qp = qg + hb + (size_t)qr * DH + half * 8;
  bf16x8 qf[4];
  #pragma unroll
  for (int s = 0; s < 4; ++s) qf[s] = *(const bf16x8*)(qp + s * 16);

  f32x16 o0 = {}, o1 = {};          // O^T[dh = m*32 + (reg&3)+8*(reg>>2)+4*half][q]
  float lrun = 0.0f;                // per-lane half-sum; cross-half fold at epilogue

  // K stage: op j (=wid*2+i) fills slots [j*64, j*64+64); slot (j*64+l) holds
  // K[k0 + (j>>2)*32 + (l&31)][(j&3)*16 + (l>>5)*8 ..+8] -> A-frag reads lane*16B linear
  auto stage = [&](int kt, int bb) {
    int k0 = kt * 64;
    #pragma unroll
    for (int i = 0; i < 2; ++i) {
      int j = wid * 2 + i;
      int g = j >> 2, s = j & 3;
      const short* src = kg_hb + (size_t)(k0 + g * 32 + q) * DH + s * 16 + half * 8;
      dma16(src, KbufL + bb * 4096 + j * 512);
    }
  };

  stage(kt0, 0);                    // prefetch distance 2
  stage(kt0 + 1, 1);

  for (int kt = kt0; kt <= kt1; ++kt) {
    int rb = (kt - kt0) % 3;
    int k0 = kt * 64;

    // own DMA(kt) is transitively retired by last iteration's V-reg waits (in-order
    // vmcnt); guard is ~free when satisfied. Then barrier: all waves' DMA(kt) landed,
    // all waves done reading buf[(kt+2)%3].
    asm volatile("s_waitcnt vmcnt(2)" ::: "memory");
    __builtin_amdgcn_s_barrier();

    // V A-frags from global (L2-resident): issue first (latency hides under QK+softmax);
    // MUST precede DMA issue so the PV V-wait doesn't transitively drain DMA(kt+2).
    bf16x8 vf0[4], vf1[4];
    #pragma unroll
    for (int s = 0; s < 4; ++s) {
      vf0[s] = *(const bf16x8*)(vT_hb + (size_t)q * NPAD + k0 + s * 16 + half * 8);
      vf1[s] = *(const bf16x8*)(vT_hb + (size_t)(32 + q) * NPAD + k0 + s * 16 + half * 8);
    }
    __builtin_amdgcn_sched_barrier(0);
    if (kt + 2 <= kt1) stage(kt + 2, (kt - kt0 + 2) % 3);
    __builtin_amdgcn_sched_barrier(0);

    // ---- S^T = K * Q^T : two 32-key groups, 4 k-steps of 16 ----
    const short* Kc = KbufR + rb * 4096;
    f32x16 sA = {}, sB = {};
    __builtin_amdgcn_s_setprio(1);
    #pragma unroll
    for (int s = 0; s < 4; ++s) {
      bf16x8 kf0 = *(const bf16x8*)&Kc[(0 * 4 + s) * 512 + lane * 8];
      bf16x8 kf1 = *(const bf16x8*)&Kc[(1 * 4 + s) * 512 + lane * 8];
      sA = __builtin_amdgcn_mfma_f32_32x32x16_bf16(kf0, qf[s], sA, 0, 0, 0);
      sB = __builtin_amdgcn_mfma_f32_32x32x16_bf16(kf1, qf[s], sB, 0, 0, 0);
    }
    __builtin_amdgcn_s_setprio(0);

    // mask invalid keys (final tile only; wave-uniform branch)
    if (k0 + 64 > N_) {
      #pragma unroll
      for (int rr = 0; rr < 16; ++rr) {
        int key = (rr & 3) + 8 * (rr >> 2) + 4 * half;
        if (k0 + key >= N_)      sA[rr] = -1e30f;
        if (k0 + 32 + key >= N_) sB[rr] = -1e30f;
      }
    }

    // ---- p = 2^s in place + per-lane row-sum ----
    float vsum = 0.0f;
    #pragma unroll
    for (int rr = 0; rr < 16; ++rr) {
      sA[rr] = hexp2(sA[rr]); vsum += sA[rr];
      sB[rr] = hexp2(sB[rr]); vsum += sB[rr];
    }
    lrun += vsum;

    // ---- pack pairs + permlane32_swap -> P^T B-frags, all in registers ----
    unsigned w[4][4];
    #pragma unroll
    for (int g = 0; g < 2; ++g) {
      #pragma unroll
      for (int fs = 0; fs < 2; ++fs) {
        int b0 = fs * 8;
        float e0, e1, e2, e3, e4, e5, e6, e7;
        if (g == 0) {
          e0 = sA[b0+0]; e1 = sA[b0+1]; e2 = sA[b0+2]; e3 = sA[b0+3];
          e4 = sA[b0+4]; e5 = sA[b0+5]; e6 = sA[b0+6]; e7 = sA[b0+7];
        } else {
          e0 = sB[b0+0]; e1 = sB[b0+1]; e2 = sB[b0+2]; e3 = sB[b0+3];
          e4 = sB[b0+4]; e5 = sB[b0+5]; e6 = sB[b0+6]; e7 = sB[b0+7];
        }
        unsigned X1 = pack_trunc(e0, e1);
        unsigned X2 = pack_trunc(e2, e3);
        unsigned Y1 = pack_trunc(e4, e5);
        unsigned Y2 = pack_trunc(e6, e7);
        asm("v_permlane32_swap_b32 %0, %1" : "+v"(X1), "+v"(Y1));
        asm("v_permlane32_swap_b32 %0, %1" : "+v"(X2), "+v"(Y2));
        int kst = g * 2 + fs;
        w[kst][0] = X1; w[kst][1] = X2; w[kst][2] = Y1; w[kst][3] = Y2;
      }
    }

    // ---- O^T += V^T * P^T ----
    __builtin_amdgcn_s_setprio(1);
    #pragma unroll
    for (int kst = 0; kst < 4; ++kst) {
      union { unsigned u[4]; bf16x8 v; } bw;
      bw.u[0] = w[kst][0]; bw.u[1] = w[kst][1]; bw.u[2] = w[kst][2]; bw.u[3] = w[kst][3];
      o0 = __builtin_amdgcn_mfma_f32_32x32x16_bf16(vf0[kst], bw.v, o0, 0, 0, 0);
      o1 = __builtin_amdgcn_mfma_f32_32x32x16_bf16(vf1[kst], bw.v, o1, 0, 0, 0);
    }
    __builtin_amdgcn_s_setprio(0);
    // no trailing barrier: top-of-loop guard+barrier covers buffer reuse
  }

  lrun += __shfl_xor(lrun, 32, 64);   // fold the two lane-halves of each q-column

  // epilogue: unnormalized partial write. Opart[ks][bh][NPAD][64] bf16, lpart[ks][bh][NPAD]
  int qrow = q0 + q;
  if (qrow < N_) {
    size_t ob = (((size_t)ks * 32 + bh) * NPAD + qrow) * 64;
    #pragma unroll
    for (int m = 0; m < 2; ++m) {
      #pragma unroll
      for (int gq = 0; gq < 4; ++gq) {
        float a0 = m ? o1[gq*4+0] : o0[gq*4+0];
        float a1 = m ? o1[gq*4+1] : o0[gq*4+1];
        float a2 = m ? o1[gq*4+2] : o0[gq*4+2];
        float a3 = m ? o1[gq*4+3] : o0[gq*4+3];
        short4 st;
        st.x = f2bf(a0); st.y = f2bf(a1); st.z = f2bf(a2); st.w = f2bf(a3);
        int dh = m * 32 + gq * 8 + half * 4;
        *(short4*)(Opart + ob + dh) = st;
      }
    }
    if (half == 0) lpart[((size_t)ks * 32 + bh) * NPAD + qrow] = lrun;
  }
}

// ------------- combine: attn_out = (O0+O1)/(l0+l1), bf16 -------------
__global__ __launch_bounds__(256) void combine_kernel(const short* __restrict__ Opart,
                                                      const float* __restrict__ lpart,
                                                      short* __restrict__ attn_out) {
  int idx = blockIdx.x * 256 + threadIdx.x;
  const int total = 32 * N_ * 16;          // 4 dh elems per thread
  if (idx >= total) return;
  int c4 = idx & 15;
  int t = idx >> 4;
  int n = t % N_;
  int bh = t / N_;
  int b = bh >> 4, h = bh & 15;
  const size_t halfO = (size_t)32 * NPAD * 64;
  size_t off = ((size_t)bh * NPAD + n) * 64 + c4 * 4;
  short4 a  = *(const short4*)(Opart + off);
  short4 bb = *(const short4*)(Opart + halfO + off);
  float la = lpart[(size_t)bh * NPAD + n];
  float lb = lpart[(size_t)32 * NPAD + (size_t)bh * NPAD + n];
  float inv = 1.0f / (la + lb);
  short4 st;
  st.x = f2bf((bf2f(a.x) + bf2f(bb.x)) * inv);
  st.y = f2bf((bf2f(a.y) + bf2f(bb.y)) * inv);
  st.z = f2bf((bf2f(a.z) + bf2f(bb.z)) * inv);
  st.w = f2bf((bf2f(a.w) + bf2f(bb.w)) * inv);
  size_t rowb = ((size_t)(b * N_ + n)) * (H_ * DH) + h * DH + c4 * 4;
  *(short4*)(attn_out + rowb) = st;
}

// ---------------- launcher ----------------
extern "C" void kernel_launch(void* const* d_in, const int* in_sizes, int n_in,
                              void* d_out, int out_size, void* d_ws, size_t ws_size,
                              hipStream_t stream) {
  const float* x     = (const float*)d_in[0];
  const float* gamma = (const float*)d_in[1];
  const float* beta  = (const float*)d_in[2];
  const float* w_qkv = (const float*)d_in[3];
  const float* w_out = (const float*)d_in[4];

  short* wqkvT = (short*)d_ws;                         // [3072][1024]
  short* woutT = wqkvT + (size_t)3072 * 1024;          // [1024][1024]
  short* xn    = woutT + (size_t)1024 * 1024;          // [4224][1024] (aliased as attn_out later)
  short* qkv   = xn    + (size_t)MPAD * 1024;          // [4224][3072] (aliased as Opart/lpart later)
  short* qg    = qkv   + (size_t)MPAD * 3072;          // [2][16][2112][64]
  short* kg    = qg    + (size_t)B_ * H_ * NPAD * DH;
  short* vTg   = kg    + (size_t)B_ * H_ * NPAD * DH;  // [2][16][64][2112]
  short* attn_out = xn;                                // xn dead after QKV GEMM
  short* Opart = qkv;                                  // [2][32][2112][64] bf16 (qkv dead after rope)
  float* lpart = (float*)(qkv + (size_t)2 * 32 * NPAD * 64);  // [2][32][2112] fp32

  ln_kernel<<<MROWS, 256, 0, stream>>>(x, gamma, beta, xn);
  {
    dim3 g(1024 / 64, 3072 / 64);          // LDS-tiled coalesced transpose
    transpose_tiled<<<g, 256, 0, stream>>>(w_qkv, wqkvT, 1024, 3072);
  }
  {
    dim3 g(1024 / 64, 1024 / 64);
    transpose_tiled<<<g, 256, 0, stream>>>(w_out, woutT, 1024, 1024);
  }
  {
    dim3 g(MPAD / 128, 3072 / 128);        // 33 x 24
    gemm128<unsigned short><<<g, 256, 0, stream>>>(xn, wqkvT, (unsigned short*)qkv, MROWS, 3072, 1024);
  }
  {
    dim3 g(33, 32);                        // 64-token tiles x (b,h)
    rope_kernel<<<g, 256, 0, stream>>>(qkv, qg, kg, vTg);
  }
  attn_kernel<<<8 * 4 * 17 * 2, 256, 0, stream>>>(qg, kg, vTg, Opart, lpart);   // 1088 wg
  combine_kernel<<<(32 * N_ * 16 + 255) / 256, 256, 0, stream>>>(Opart, lpart, attn_out);
  {
    dim3 g(MPAD / 128, 1024 / 128);        // 33 x 8
    gemm128<float><<<g, 256, 0, stream>>>(attn_out, woutT, (float*)d_out, MROWS, 1024, 1024);
  }
}

// Round 7
// 245.588 us; speedup vs baseline: 1.5874x; 1.1925x over previous
//
#include <hip/hip_runtime.h>

// ---- problem constants ----
#define B_    2
#define N_    2049
#define NPAD  2112          // keys padded to multiple of 64
#define D_    1024
#define H_    16
#define DH    64
#define MROWS (B_ * N_)     // 4098
#define MPAD  4224          // MROWS padded to multiple of 128 (GEMM block tile)
#define QSCALE 0.18033688011117674f   // 0.125 * log2(e): softmax in exp2 domain

using bf16x8 = __attribute__((ext_vector_type(8))) short;
using f32x4  = __attribute__((ext_vector_type(4))) float;
using f32x16 = __attribute__((ext_vector_type(16))) float;

#define AS1 __attribute__((address_space(1)))
#define AS3 __attribute__((address_space(3)))

__device__ __forceinline__ float bf2f(short s) {
  union { unsigned u; float f; } a; a.u = ((unsigned)(unsigned short)s) << 16; return a.f;
}
__device__ __forceinline__ short f2bf(float f) {
  union { float f; unsigned u; } a; a.f = f;
  unsigned r = a.u + 0x7fffu + ((a.u >> 16) & 1u);   // round-to-nearest-even
  return (short)(r >> 16);
}
// truncation pack of two fp32 -> bf16x2
__device__ __forceinline__ unsigned pack_trunc(float lo, float hi) {
  union { float f; unsigned u; } a, b; a.f = lo; b.f = hi;
  return (b.u & 0xffff0000u) | (a.u >> 16);
}
// hardware 2^x (v_exp_f32)
__device__ __forceinline__ float hexp2(float x) { return __builtin_amdgcn_exp2f(x); }
// async global->LDS DMA, 16 B/lane; LDS dst is wave-uniform base (+lane*16 by HW)
__device__ __forceinline__ void dma16(const short* g, AS3 short* l) {
  __builtin_amdgcn_global_load_lds((const AS1 unsigned*)g, (AS3 unsigned*)l, 16, 0, 0);
}

// ---------------- LayerNorm: fp32 in -> bf16 out ----------------
__global__ __launch_bounds__(256) void ln_kernel(const float* __restrict__ x,
                                                 const float* __restrict__ gamma,
                                                 const float* __restrict__ beta,
                                                 short* __restrict__ xn) {
  int row = blockIdx.x;
  int tid = threadIdx.x;
  const float4 v = ((const float4*)(x + (size_t)row * D_))[tid];
  float s  = v.x + v.y + v.z + v.w;
  float ss = v.x * v.x + v.y * v.y + v.z * v.z + v.w * v.w;
  for (int o = 1; o < 64; o <<= 1) { s += __shfl_xor(s, o, 64); ss += __shfl_xor(ss, o, 64); }
  __shared__ float sb[4], s2b[4];
  int wid = tid >> 6;
  if ((tid & 63) == 0) { sb[wid] = s; s2b[wid] = ss; }
  __syncthreads();
  float st  = sb[0] + sb[1] + sb[2] + sb[3];
  float sst = s2b[0] + s2b[1] + s2b[2] + s2b[3];
  float mu  = st * (1.0f / D_);
  float var = sst * (1.0f / D_) - mu * mu;
  float rs  = rsqrtf(var + 1e-5f);
  const float4 g  = ((const float4*)gamma)[tid];
  const float4 be = ((const float4*)beta)[tid];
  short4 o4;
  o4.x = f2bf((v.x - mu) * rs * g.x + be.x);
  o4.y = f2bf((v.y - mu) * rs * g.y + be.y);
  o4.z = f2bf((v.z - mu) * rs * g.z + be.z);
  o4.w = f2bf((v.w - mu) * rs * g.w + be.w);
  ((short4*)(xn + (size_t)row * D_))[tid] = o4;
}

// ------------- LDS-tiled transpose+cast: fp32 [K][Nn] -> bf16 [Nn][K] -------------
__global__ __launch_bounds__(256) void transpose_tiled(const float* __restrict__ in,
                                                       short* __restrict__ out,
                                                       int K, int Nn) {
  __shared__ float T[64][65];       // +1 pad: column reads hit distinct banks
  int k0 = blockIdx.x * 64;         // K-tile base
  int n0 = blockIdx.y * 64;         // N-tile base
  int t = threadIdx.x;
  int r = t >> 2, c0 = (t & 3) * 16;
  const float* ip = in + (size_t)(k0 + r) * Nn + n0 + c0;
  #pragma unroll
  for (int j = 0; j < 4; ++j) {
    float4 v = *(const float4*)(ip + j * 4);
    T[r][c0 + j * 4 + 0] = v.x; T[r][c0 + j * 4 + 1] = v.y;
    T[r][c0 + j * 4 + 2] = v.z; T[r][c0 + j * 4 + 3] = v.w;
  }
  __syncthreads();
  // write: row n = n0 + (t>>2), orig-k cols c0..c0+15, bf16 coalesced
  bf16x8 w0, w1;
  #pragma unroll
  for (int j = 0; j < 8; ++j) {
    w0[j] = f2bf(T[c0 + j][r]);
    w1[j] = f2bf(T[c0 + 8 + j][r]);
  }
  short* op = out + (size_t)(n0 + r) * K + k0 + c0;
  *(bf16x8*)op = w0;
  *(bf16x8*)(op + 8) = w1;
}

// ------------- m97-style 128x128 GEMM: C[M][Ncols] = A[M][K] * BT[Ncols][K]^T -------------
#define BM 128
#define BK 32
template <typename OutT>
__global__ __launch_bounds__(256) void gemm128(const short* __restrict__ A,
                                               const short* __restrict__ BT,
                                               OutT* __restrict__ C,
                                               int Mstore, int Ncols, int K) {
  int lane = threadIdx.x & 63, wid = threadIdx.x >> 6;
  int quad = lane >> 4, l16 = lane & 15;
  int wr = wid >> 1, wc = wid & 1;
  int m0 = blockIdx.x * BM;
  int n0 = blockIdx.y * BM;

  __shared__ __align__(16) short Abuf[2][BM * BK];   // [row][k] row-major, 8 KB each
  __shared__ __align__(16) short Bbuf[2][BM * BK];
  AS3 short* AbufL = (AS3 short*)&Abuf[0][0];
  AS3 short* BbufL = (AS3 short*)&Bbuf[0][0];

  f32x4 acc[4][4] = {};

  int lrow = lane >> 2, lcol8 = (lane & 3) * 8;
  const short* Ag = A  + (size_t)(m0 + lrow) * K + lcol8;
  const short* Bg = BT + (size_t)(n0 + lrow) * K + lcol8;

  auto stage = [&](int kt, int bb) {
    int k0 = kt * BK;
    #pragma unroll
    for (int i = 0; i < 2; ++i) {
      int j = wid * 2 + i;                  // slab 0..7 (16 rows each)
      dma16(Ag + (size_t)j * 16 * K + k0, AbufL + bb * (BM * BK) + j * 512);
      dma16(Bg + (size_t)j * 16 * K + k0, BbufL + bb * (BM * BK) + j * 512);
    }
  };

  stage(0, 0);
  __syncthreads();

  int KT = K / BK;
  for (int kt = 0; kt < KT; ++kt) {
    int cur = kt & 1;
    if (kt + 1 < KT) stage(kt + 1, cur ^ 1);
    const short* Ab = &Abuf[cur][0];
    const short* Bb = &Bbuf[cur][0];
    bf16x8 af[4], bfr[4];
    #pragma unroll
    for (int s = 0; s < 4; ++s)
      af[s] = *(const bf16x8*)&Ab[(wr * 64 + s * 16 + l16) * BK + quad * 8];
    #pragma unroll
    for (int t = 0; t < 4; ++t)
      bfr[t] = *(const bf16x8*)&Bb[(wc * 64 + t * 16 + l16) * BK + quad * 8];
    #pragma unroll
    for (int s = 0; s < 4; ++s)
      #pragma unroll
      for (int t = 0; t < 4; ++t)
        acc[s][t] = __builtin_amdgcn_mfma_f32_16x16x32_bf16(af[s], bfr[t], acc[s][t], 0, 0, 0);
    __syncthreads();
  }

  #pragma unroll
  for (int s = 0; s < 4; ++s)
    #pragma unroll
    for (int r = 0; r < 4; ++r) {
      int row = m0 + wr * 64 + s * 16 + quad * 4 + r;
      if (row < Mstore) {
        size_t rb = (size_t)row * Ncols + n0 + wc * 64;
        #pragma unroll
        for (int t = 0; t < 4; ++t) {
          float val = acc[s][t][r];
          if constexpr (sizeof(OutT) == 2)
            C[rb + t * 16 + l16] = (OutT)(unsigned short)f2bf(val);
          else
            C[rb + t * 16 + l16] = (OutT)val;
        }
      }
    }
}

// ------------- RoPE v3: emits K and V in MFMA-FRAGMENT-LINEAR order -------------
// kfrag[bh][tile kt][chunk j=g*4+s][lane l][8 shorts] = K[kt*64 + g*32 + (l&31)][s*16+(l>>5)*8 ..+8]
// vfrag[bh][tile kt][chunk m*4+s ][lane l][8 shorts] = V^T[m*32+(l&31)][kt*64 + s*16+(l>>5)*8 ..+8]
// -> every attn-side load/DMA-source is base + lane*16B: fully coalesced 1KiB/instruction.
__global__ __launch_bounds__(256) void rope_kernel(const short* __restrict__ qkv,
                                                   short* __restrict__ qg,
                                                   short* __restrict__ kfrag,
                                                   short* __restrict__ vfrag) {
  int bh = blockIdx.y;              // 0..31
  int n0 = blockIdx.x * 64;         // 33 tiles cover NPAD
  int b = bh >> 4, h = bh & 15;
  int t = threadIdx.x;
  int nl = t >> 2;                  // token within tile
  int p  = t & 3;                   // dh part: pairs (p*8+j, p*8+j+32)
  int n  = n0 + nl;
  size_t hb = (size_t)bh * NPAD * DH;
  size_t ob = hb + (size_t)n * DH;

  __shared__ short Vt[64][66];      // [key-local][dh], pad 2
  __shared__ short Kt[64][66];      // [key-local][dh]

  bf16x8 oq1 = {}, oq2 = {}, ok1 = {}, ok2 = {};
  short v1s[8] = {}, v2s[8] = {};
  if (n < N_) {
    size_t ib = ((size_t)(b * N_ + n)) * 3072 + h * DH;
    bf16x8 q1v = *(const bf16x8*)(qkv + ib + p * 8);
    bf16x8 q2v = *(const bf16x8*)(qkv + ib + 32 + p * 8);
    bf16x8 k1v = *(const bf16x8*)(qkv + ib + 1024 + p * 8);
    bf16x8 k2v = *(const bf16x8*)(qkv + ib + 1024 + 32 + p * 8);
    bf16x8 v1v = *(const bf16x8*)(qkv + ib + 2048 + p * 8);
    bf16x8 v2v = *(const bf16x8*)(qkv + ib + 2048 + 32 + p * 8);
    #pragma unroll
    for (int j = 0; j < 8; ++j) {
      int i = p * 8 + j;
      float q1 = bf2f(q1v[j]), q2 = bf2f(q2v[j]);
      float k1 = bf2f(k1v[j]), k2 = bf2f(k2v[j]);
      if (n > 0) {              // cls token excluded from RoPE
        float ang = (float)(n - 1) * powf(10000.0f, -(float)i * (1.0f / 32.0f));
        float sn, cs; sincosf(ang, &sn, &cs);
        float nq1 = q1 * cs - q2 * sn, nq2 = q2 * cs + q1 * sn;
        float nk1 = k1 * cs - k2 * sn, nk2 = k2 * cs + k1 * sn;
        q1 = nq1; q2 = nq2; k1 = nk1; k2 = nk2;
      }
      oq1[j] = f2bf(q1 * QSCALE); oq2[j] = f2bf(q2 * QSCALE);  // scale*log2e folded into q
      ok1[j] = f2bf(k1); ok2[j] = f2bf(k2);
      v1s[j] = v1v[j]; v2s[j] = v2v[j];
    }
  }
  // q row-major stores (zero rows for padding) — unchanged
  *(bf16x8*)(qg + ob + p * 8)      = oq1;
  *(bf16x8*)(qg + ob + 32 + p * 8) = oq2;
  // stage K and V tiles to LDS [key][dh]
  #pragma unroll
  for (int j = 0; j < 8; ++j) {
    Vt[nl][p * 8 + j]      = v1s[j];
    Vt[nl][32 + p * 8 + j] = v2s[j];
    Kt[nl][p * 8 + j]      = ok1[j];
    Kt[nl][32 + p * 8 + j] = ok2[j];
  }
  __syncthreads();

  // fragment emission: thread t -> lane l = t&63, chunk s-index c = t>>6 (0..3)
  int l = t & 63, c = t >> 6;
  int lk = l & 31, hi = l >> 5;
  size_t tb = hb + (size_t)(n0 >> 6) * 4096;      // 4096 shorts per (bh, tile)
  bf16x8 wv0, wv1, wk0, wk1;
  #pragma unroll
  for (int i = 0; i < 8; ++i) {
    int keyr = c * 16 + hi * 8 + i;               // key-local for vfrag / dh for kfrag
    wv0[i] = Vt[keyr][lk];                        // m=0: dh = lk
    wv1[i] = Vt[keyr][32 + lk];                   // m=1: dh = 32+lk
    wk0[i] = Kt[lk][keyr];                        // g=0: key = lk,   dh = c*16+hi*8+i
    wk1[i] = Kt[32 + lk][keyr];                   // g=1: key = 32+lk
  }
  // fully-coalesced stores: consecutive t -> consecutive 16B
  *(bf16x8*)(vfrag + tb + (size_t)(0 * 4 + c) * 512 + l * 8) = wv0;
  *(bf16x8*)(vfrag + tb + (size_t)(4 + c) * 512 + l * 8)     = wv1;
  *(bf16x8*)(kfrag + tb + (size_t)(0 * 4 + c) * 512 + l * 8) = wk0;
  *(bf16x8*)(kfrag + tb + (size_t)(4 + c) * 512 + l * 8)     = wk1;
}

// ------------- flash attention v8: r6 schedule, fragment-linear (coalesced) K/V ---------
// Evidence ledger: r0/r2/r3/r6 (4 different schedules) all = 110-121us -> schedule is not
// the bottleneck. Shared invariant: V loads and K-DMA sources were 32-line GATHERS
// (lane l -> dh-row l&31, rows 4224B apart). In a latency-bound regime each such load
// completes at the MAX of 32 scattered line fetches and vmcnt retires in order -> one
// straggler stalls the chain. v8: rope pre-permutes K/V into fragment order so every
// load/DMA-source is base + lane*16B (contiguous 1KiB, 16 sequential lines). The attn
// kernel's LDS contents, MFMA stream, softmax, and schedule are byte-identical to r6.
// Layouts (mfma_f32_32x32x16_bf16): A: lane l holds A[m=l&31][k=(l>>5)*8+j];
// B: B[k=(l>>5)*8+j][n=l&31]; C/D: col=l&31, row=(reg&3)+8*(reg>>2)+4*(l>>5).
__global__ __launch_bounds__(256, 3) void attn_kernel(const short* __restrict__ qg,
                                                      const short* __restrict__ kfrag,
                                                      const short* __restrict__ vfrag,
                                                      short* __restrict__ Opart,
                                                      float* __restrict__ lpart) {
  // XCD-clustered decode: blk&7 -> XCD; 4 heads per XCD
  int blk = blockIdx.x;             // 0..1087
  int xcd = blk & 7;
  int t_  = blk >> 3;               // 0..135
  int bh  = xcd * 4 + (t_ & 3);
  int u   = t_ >> 2;                // 0..33
  int ks  = (u >= 17) ? 1 : 0;
  int qblk = u - ks * 17;           // 0..16
  int kt0 = ks * 17, kt1 = ks ? 32 : 16;   // inclusive key-tile range

  int lane = threadIdx.x & 63, wid = threadIdx.x >> 6;
  int q    = lane & 31;             // q-column within wave's 32-row tile
  int half = lane >> 5;             // 0/1: lane half
  int q0   = qblk * 128 + wid * 32;
  size_t hb = (size_t)bh * NPAD * DH;
  const short* kf_hb = kfrag + hb;
  const short* vf_hb = vfrag + hb;

  __shared__ __align__(16) short Kbuf[3][8 * 512];   // 24 KB, triple-buffered
  AS3 short* KbufL = (AS3 short*)&Kbuf[0][0];
  const short* KbufR = &Kbuf[0][0];

  // Q B-frags (persistent): lane reads its q-row; k = kstep*16 + half*8 + j
  int qr = q0 + q; if (qr >= NPAD) qr = 0;   // clamp; garbage column never stored
  const short* qp = qg + hb + (size_t)qr * DH + half * 8;
  bf16x8 qf[4];
  #pragma unroll
  for (int s = 0; s < 4; ++s) qf[s] = *(const bf16x8*)(qp + s * 16);

  f32x16 o0 = {}, o1 = {};          // O^T[dh = m*32 + (reg&3)+8*(reg>>2)+4*half][q]
  float lrun = 0.0f;                // per-lane half-sum; cross-half fold at epilogue

  // K stage: chunk j source is CONTIGUOUS (base + lane*16B) in fragment order
  auto stage = [&](int kt, int bb) {
    const short* src = kf_hb + (size_t)kt * 4096;
    #pragma unroll
    for (int i = 0; i < 2; ++i) {
      int j = wid * 2 + i;
      dma16(src + j * 512 + lane * 8, KbufL + bb * 4096 + j * 512);
    }
  };

  stage(kt0, 0);                    // prefetch distance 2
  stage(kt0 + 1, 1);

  for (int kt = kt0; kt <= kt1; ++kt) {
    int rb = (kt - kt0) % 3;
    int k0 = kt * 64;

    // own DMA(kt) is transitively retired by last iteration's V-reg waits (in-order
    // vmcnt); guard is ~free when satisfied. Then barrier: all waves' DMA(kt) landed,
    // all waves done reading buf[(kt+2)%3].
    asm volatile("s_waitcnt vmcnt(2)" ::: "memory");
    __builtin_amdgcn_s_barrier();

    // V A-frags: fragment-linear, fully coalesced (base + lane*16B). Issue first so
    // the PV V-wait doesn't transitively drain DMA(kt+2).
    const short* vt = vf_hb + (size_t)kt * 4096;
    bf16x8 vf0[4], vf1[4];
    #pragma unroll
    for (int s = 0; s < 4; ++s) {
      vf0[s] = *(const bf16x8*)(vt + (0 * 4 + s) * 512 + lane * 8);
      vf1[s] = *(const bf16x8*)(vt + (4 + s) * 512 + lane * 8);
    }
    __builtin_amdgcn_sched_barrier(0);
    if (kt + 2 <= kt1) stage(kt + 2, (kt - kt0 + 2) % 3);
    __builtin_amdgcn_sched_barrier(0);

    // ---- S^T = K * Q^T : two 32-key groups, 4 k-steps of 16 ----
    const short* Kc = KbufR + rb * 4096;
    f32x16 sA = {}, sB = {};
    __builtin_amdgcn_s_setprio(1);
    #pragma unroll
    for (int s = 0; s < 4; ++s) {
      bf16x8 kf0 = *(const bf16x8*)&Kc[(0 * 4 + s) * 512 + lane * 8];
      bf16x8 kf1 = *(const bf16x8*)&Kc[(1 * 4 + s) * 512 + lane * 8];
      sA = __builtin_amdgcn_mfma_f32_32x32x16_bf16(kf0, qf[s], sA, 0, 0, 0);
      sB = __builtin_amdgcn_mfma_f32_32x32x16_bf16(kf1, qf[s], sB, 0, 0, 0);
    }
    __builtin_amdgcn_s_setprio(0);

    // mask invalid keys (final tile only; wave-uniform branch)
    if (k0 + 64 > N_) {
      #pragma unroll
      for (int rr = 0; rr < 16; ++rr) {
        int key = (rr & 3) + 8 * (rr >> 2) + 4 * half;
        if (k0 + key >= N_)      sA[rr] = -1e30f;
        if (k0 + 32 + key >= N_) sB[rr] = -1e30f;
      }
    }

    // ---- p = 2^s in place + per-lane row-sum ----
    float vsum = 0.0f;
    #pragma unroll
    for (int rr = 0; rr < 16; ++rr) {
      sA[rr] = hexp2(sA[rr]); vsum += sA[rr];
      sB[rr] = hexp2(sB[rr]); vsum += sB[rr];
    }
    lrun += vsum;

    // ---- pack pairs + permlane32_swap -> P^T B-frags, all in registers ----
    unsigned w[4][4];
    #pragma unroll
    for (int g = 0; g < 2; ++g) {
      #pragma unroll
      for (int fs = 0; fs < 2; ++fs) {
        int b0 = fs * 8;
        float e0, e1, e2, e3, e4, e5, e6, e7;
        if (g == 0) {
          e0 = sA[b0+0]; e1 = sA[b0+1]; e2 = sA[b0+2]; e3 = sA[b0+3];
          e4 = sA[b0+4]; e5 = sA[b0+5]; e6 = sA[b0+6]; e7 = sA[b0+7];
        } else {
          e0 = sB[b0+0]; e1 = sB[b0+1]; e2 = sB[b0+2]; e3 = sB[b0+3];
          e4 = sB[b0+4]; e5 = sB[b0+5]; e6 = sB[b0+6]; e7 = sB[b0+7];
        }
        unsigned X1 = pack_trunc(e0, e1);
        unsigned X2 = pack_trunc(e2, e3);
        unsigned Y1 = pack_trunc(e4, e5);
        unsigned Y2 = pack_trunc(e6, e7);
        asm("v_permlane32_swap_b32 %0, %1" : "+v"(X1), "+v"(Y1));
        asm("v_permlane32_swap_b32 %0, %1" : "+v"(X2), "+v"(Y2));
        int kst = g * 2 + fs;
        w[kst][0] = X1; w[kst][1] = X2; w[kst][2] = Y1; w[kst][3] = Y2;
      }
    }

    // ---- O^T += V^T * P^T ----
    __builtin_amdgcn_s_setprio(1);
    #pragma unroll
    for (int kst = 0; kst < 4; ++kst) {
      union { unsigned u[4]; bf16x8 v; } bw;
      bw.u[0] = w[kst][0]; bw.u[1] = w[kst][1]; bw.u[2] = w[kst][2]; bw.u[3] = w[kst][3];
      o0 = __builtin_amdgcn_mfma_f32_32x32x16_bf16(vf0[kst], bw.v, o0, 0, 0, 0);
      o1 = __builtin_amdgcn_mfma_f32_32x32x16_bf16(vf1[kst], bw.v, o1, 0, 0, 0);
    }
    __builtin_amdgcn_s_setprio(0);
    // no trailing barrier: top-of-loop guard+barrier covers buffer reuse
  }

  lrun += __shfl_xor(lrun, 32, 64);   // fold the two lane-halves of each q-column

  // epilogue: unnormalized partial write. Opart[ks][bh][NPAD][64] bf16, lpart[ks][bh][NPAD]
  int qrow = q0 + q;
  if (qrow < N_) {
    size_t ob = (((size_t)ks * 32 + bh) * NPAD + qrow) * 64;
    #pragma unroll
    for (int m = 0; m < 2; ++m) {
      #pragma unroll
      for (int gq = 0; gq < 4; ++gq) {
        float a0 = m ? o1[gq*4+0] : o0[gq*4+0];
        float a1 = m ? o1[gq*4+1] : o0[gq*4+1];
        float a2 = m ? o1[gq*4+2] : o0[gq*4+2];
        float a3 = m ? o1[gq*4+3] : o0[gq*4+3];
        short4 st;
        st.x = f2bf(a0); st.y = f2bf(a1); st.z = f2bf(a2); st.w = f2bf(a3);
        int dh = m * 32 + gq * 8 + half * 4;
        *(short4*)(Opart + ob + dh) = st;
      }
    }
    if (half == 0) lpart[((size_t)ks * 32 + bh) * NPAD + qrow] = lrun;
  }
}

// ------------- combine: attn_out = (O0+O1)/(l0+l1), bf16 -------------
__global__ __launch_bounds__(256) void combine_kernel(const short* __restrict__ Opart,
                                                      const float* __restrict__ lpart,
                                                      short* __restrict__ attn_out) {
  int idx = blockIdx.x * 256 + threadIdx.x;
  const int total = 32 * N_ * 16;          // 4 dh elems per thread
  if (idx >= total) return;
  int c4 = idx & 15;
  int t = idx >> 4;
  int n = t % N_;
  int bh = t / N_;
  int b = bh >> 4, h = bh & 15;
  const size_t halfO = (size_t)32 * NPAD * 64;
  size_t off = ((size_t)bh * NPAD + n) * 64 + c4 * 4;
  short4 a  = *(const short4*)(Opart + off);
  short4 bb = *(const short4*)(Opart + halfO + off);
  float la = lpart[(size_t)bh * NPAD + n];
  float lb = lpart[(size_t)32 * NPAD + (size_t)bh * NPAD + n];
  float inv = 1.0f / (la + lb);
  short4 st;
  st.x = f2bf((bf2f(a.x) + bf2f(bb.x)) * inv);
  st.y = f2bf((bf2f(a.y) + bf2f(bb.y)) * inv);
  st.z = f2bf((bf2f(a.z) + bf2f(bb.z)) * inv);
  st.w = f2bf((bf2f(a.w) + bf2f(bb.w)) * inv);
  size_t rowb = ((size_t)(b * N_ + n)) * (H_ * DH) + h * DH + c4 * 4;
  *(short4*)(attn_out + rowb) = st;
}

// ---------------- launcher ----------------
extern "C" void kernel_launch(void* const* d_in, const int* in_sizes, int n_in,
                              void* d_out, int out_size, void* d_ws, size_t ws_size,
                              hipStream_t stream) {
  const float* x     = (const float*)d_in[0];
  const float* gamma = (const float*)d_in[1];
  const float* beta  = (const float*)d_in[2];
  const float* w_qkv = (const float*)d_in[3];
  const float* w_out = (const float*)d_in[4];

  short* wqkvT = (short*)d_ws;                         // [3072][1024]
  short* woutT = wqkvT + (size_t)3072 * 1024;          // [1024][1024]
  short* xn    = woutT + (size_t)1024 * 1024;          // [4224][1024] (aliased as attn_out later)
  short* qkv   = xn    + (size_t)MPAD * 1024;          // [4224][3072] (aliased as Opart/lpart later)
  short* qg    = qkv   + (size_t)MPAD * 3072;          // [2][16][2112][64]
  short* kfragG = qg    + (size_t)B_ * H_ * NPAD * DH; // fragment-linear K, same footprint
  short* vfragG = kfragG + (size_t)B_ * H_ * NPAD * DH;// fragment-linear V^T
  short* attn_out = xn;                                // xn dead after QKV GEMM
  short* Opart = qkv;                                  // [2][32][2112][64] bf16 (qkv dead after rope)
  float* lpart = (float*)(qkv + (size_t)2 * 32 * NPAD * 64);  // [2][32][2112] fp32

  ln_kernel<<<MROWS, 256, 0, stream>>>(x, gamma, beta, xn);
  {
    dim3 g(1024 / 64, 3072 / 64);          // LDS-tiled coalesced transpose
    transpose_tiled<<<g, 256, 0, stream>>>(w_qkv, wqkvT, 1024, 3072);
  }
  {
    dim3 g(1024 / 64, 1024 / 64);
    transpose_tiled<<<g, 256, 0, stream>>>(w_out, woutT, 1024, 1024);
  }
  {
    dim3 g(MPAD / 128, 3072 / 128);        // 33 x 24
    gemm128<unsigned short><<<g, 256, 0, stream>>>(xn, wqkvT, (unsigned short*)qkv, MROWS, 3072, 1024);
  }
  {
    dim3 g(33, 32);                        // 64-token tiles x (b,h)
    rope_kernel<<<g, 256, 0, stream>>>(qkv, qg, kfragG, vfragG);
  }
  attn_kernel<<<8 * 4 * 17 * 2, 256, 0, stream>>>(qg, kfragG, vfragG, Opart, lpart);   // 1088 wg
  combine_kernel<<<(32 * N_ * 16 + 255) / 256, 256, 0, stream>>>(Opart, lpart, attn_out);
  {
    dim3 g(MPAD / 128, 1024 / 128);        // 33 x 8
    gemm128<float><<<g, 256, 0, stream>>>(attn_out, woutT, (float*)d_out, MROWS, 1024, 1024);
  }
}